// Round 3
// baseline (1505.350 us; speedup 1.0000x reference)
//
#include <hip/hip_runtime.h>
#include <hip/hip_bf16.h>

#define N_FEAT 128
#define HID 16
#define NCLS 10
#define NGRAPH 1024

__device__ __forceinline__ float u2f(unsigned int u) {
    union { unsigned int u; float f; } c; c.u = u; return c.f;
}
__device__ __forceinline__ float bf2f(__hip_bfloat16 b) {
    return __bfloat162float(b);
}
// load float element i from buffer that is bf16 (isbf=1) or fp32 (isbf=0)
__device__ __forceinline__ float ldw(const void* __restrict__ p, int i, int isbf) {
    return isbf ? bf2f(((const __hip_bfloat16*)p)[i]) : ((const float*)p)[i];
}

// ---------------------------------------------------------------------------
// K0: runtime dtype probes.
// flags[0]: 1 if edge_index is int64 (odd int32 words of positive int64s are 0),
//           0 if int32 (those words are random node ids).
// flags[1]: 1 if float tensors are bf16, 0 if fp32. x ~ N(0,1): for fp32 the
//           low 16 bits of each word are uniform mantissa (exp-field of low
//           half in narrow window w.p. ~4%); for bf16 the low half is itself
//           a bf16 normal sample (in window w.p. ~99%).
__global__ void k_detect(const int* __restrict__ ei,
                         const unsigned int* __restrict__ xw,
                         int* __restrict__ flags) {
    if (blockIdx.x == 0 && threadIdx.x == 0) {
        int nz = 0;
        for (int i = 1; i < 256; i += 2) nz |= ei[i];
        flags[0] = (nz == 0) ? 1 : 0;
        int cnt = 0;
        for (int i = 0; i < 64; i++) {
            unsigned int ef = xw[i] & 0x7F80u;
            if (ef >= 0x3C00u && ef <= 0x4080u) cnt++;
        }
        flags[1] = (cnt >= 32) ? 1 : 0;
    }
}

// K0b: zero a float buffer (kernels only — no hipMemsetAsync).
__global__ void k_zero(float* __restrict__ p, int n) {
    int i = blockIdx.x * blockDim.x + threadIdx.x;
    if (i < n) p[i] = 0.0f;
}

// ---------------------------------------------------------------------------
// K1: h0[i] = emb[argmax(x[i,:])] — one 64-lane wave per node.
// Tie-break = lowest index (matches np.argmax).
__global__ void k_argmax_embed(const void* __restrict__ x,
                               const void* __restrict__ emb,
                               const int* __restrict__ flags,
                               float* __restrict__ h, int n) {
    int wave = (int)((blockIdx.x * (unsigned)blockDim.x + threadIdx.x) >> 6);
    int lane = threadIdx.x & 63;
    if (wave >= n) return;
    int isbf = flags[1];
    float v0, v1;
    if (isbf) {
        const unsigned int* row =
            (const unsigned int*)((const __hip_bfloat16*)x + (size_t)wave * N_FEAT);
        unsigned int u = row[lane];
        v0 = u2f(u << 16);          // feature 2*lane
        v1 = u2f(u & 0xffff0000u);  // feature 2*lane+1
    } else {
        const float2* row = (const float2*)((const float*)x + (size_t)wave * N_FEAT);
        float2 u = row[lane];
        v0 = u.x; v1 = u.y;
    }
    float bv; int bi;
    if (v1 > v0) { bv = v1; bi = 2 * lane + 1; }
    else         { bv = v0; bi = 2 * lane; }
    #pragma unroll
    for (int off = 1; off < 64; off <<= 1) {
        float ov = __shfl_xor(bv, off);
        int   oi = __shfl_xor(bi, off);
        if (ov > bv || (ov == bv && oi < bi)) { bv = ov; bi = oi; }
    }
    if (lane < HID)
        h[(size_t)wave * HID + lane] = ldw(emb, bi * HID + lane, isbf);
}

// ---------------------------------------------------------------------------
// K2: degree count (float; reused by all 3 layers)
__global__ void k_deg(const int* __restrict__ ei, const int* __restrict__ flags,
                      float* __restrict__ deg, int e) {
    int i = blockIdx.x * blockDim.x + threadIdx.x;
    if (i >= e) return;
    int sh = flags[0];
    int d = ei[((size_t)(e + i)) << sh];
    atomicAdd(&deg[d], 1.0f);
}

// ---------------------------------------------------------------------------
// K3: agg[dst[e], f] += h[src[e], f].  16 lanes/edge: lane f handles one float
// of the 64B source row (coalesced), 1 atomic per lane.
__global__ void k_scatter(const int* __restrict__ ei, const int* __restrict__ flags,
                          const float* __restrict__ h, float* __restrict__ agg,
                          int e) {
    unsigned int gid = blockIdx.x * (unsigned)blockDim.x + threadIdx.x;
    int eid = (int)(gid >> 4);
    int f   = (int)(gid & 15u);
    if (eid >= e) return;
    int sh = flags[0];
    int s = ei[((size_t)eid) << sh];
    int d = ei[((size_t)(e + eid)) << sh];
    atomicAdd(&agg[(size_t)d * HID + f], h[(size_t)s * HID + f]);
}

// ---------------------------------------------------------------------------
// K4: combine layers 1/2: out = Wl@(agg/max(deg,1)) + b + Wr@h ; L2-norm ; ReLU
__global__ void k_combine(const float* __restrict__ agg, const float* __restrict__ hin,
                          const float* __restrict__ deg,
                          const void* __restrict__ Wl, const void* __restrict__ bia,
                          const void* __restrict__ Wr, const int* __restrict__ flags,
                          float* __restrict__ hout, int n) {
    __shared__ float wl[HID][HID], wr[HID][HID], bb[HID];
    int t = threadIdx.x;
    int isbf = flags[1];
    if (t < HID * HID) {
        wl[t >> 4][t & 15] = ldw(Wl, t, isbf);
        wr[t >> 4][t & 15] = ldw(Wr, t, isbf);
    }
    if (t < HID) bb[t] = ldw(bia, t, isbf);
    __syncthreads();
    int i = blockIdx.x * blockDim.x + t;
    if (i >= n) return;
    float inv = 1.0f / fmaxf(deg[i], 1.0f);
    float a[HID], hv[HID], o[HID];
    const float4* ap = (const float4*)(agg + (size_t)i * HID);
    const float4* hp = (const float4*)(hin + (size_t)i * HID);
    #pragma unroll
    for (int q = 0; q < 4; q++) {
        float4 av = ap[q], hvv = hp[q];
        a[4*q+0] = av.x * inv; a[4*q+1] = av.y * inv; a[4*q+2] = av.z * inv; a[4*q+3] = av.w * inv;
        hv[4*q+0] = hvv.x; hv[4*q+1] = hvv.y; hv[4*q+2] = hvv.z; hv[4*q+3] = hvv.w;
    }
    float ss = 0.0f;
    #pragma unroll
    for (int oi = 0; oi < HID; oi++) {
        float acc = bb[oi];
        #pragma unroll
        for (int k = 0; k < HID; k++)
            acc += a[k] * wl[oi][k] + hv[k] * wr[oi][k];
        o[oi] = acc;
        ss += acc * acc;
    }
    float innorm = 1.0f / fmaxf(sqrtf(ss), 1e-12f);
    float4* op = (float4*)(hout + (size_t)i * HID);
    #pragma unroll
    for (int q = 0; q < 4; q++) {
        float4 v;
        v.x = fmaxf(o[4*q+0] * innorm, 0.0f);
        v.y = fmaxf(o[4*q+1] * innorm, 0.0f);
        v.z = fmaxf(o[4*q+2] * innorm, 0.0f);
        v.w = fmaxf(o[4*q+3] * innorm, 0.0f);
        op[q] = v;
    }
}

// ---------------------------------------------------------------------------
// K5: layer-3 combine (out dim 10, no ReLU) -> h3 [n,10] fp32
__global__ void k_combine3(const float* __restrict__ agg, const float* __restrict__ hin,
                           const float* __restrict__ deg,
                           const void* __restrict__ Wl, const void* __restrict__ bia,
                           const void* __restrict__ Wr, const int* __restrict__ flags,
                           float* __restrict__ h3, int n) {
    __shared__ float wl[NCLS][HID], wr[NCLS][HID], bb[NCLS];
    int t = threadIdx.x;
    int isbf = flags[1];
    if (t < NCLS * HID) {
        wl[t >> 4][t & 15] = ldw(Wl, t, isbf);
        wr[t >> 4][t & 15] = ldw(Wr, t, isbf);
    }
    if (t < NCLS) bb[t] = ldw(bia, t, isbf);
    __syncthreads();
    int i = blockIdx.x * blockDim.x + t;
    if (i >= n) return;
    float inv = 1.0f / fmaxf(deg[i], 1.0f);
    float a[HID], hv[HID], o[NCLS];
    const float4* ap = (const float4*)(agg + (size_t)i * HID);
    const float4* hp = (const float4*)(hin + (size_t)i * HID);
    #pragma unroll
    for (int q = 0; q < 4; q++) {
        float4 av = ap[q], hvv = hp[q];
        a[4*q+0] = av.x * inv; a[4*q+1] = av.y * inv; a[4*q+2] = av.z * inv; a[4*q+3] = av.w * inv;
        hv[4*q+0] = hvv.x; hv[4*q+1] = hvv.y; hv[4*q+2] = hvv.z; hv[4*q+3] = hvv.w;
    }
    float ss = 0.0f;
    #pragma unroll
    for (int oi = 0; oi < NCLS; oi++) {
        float acc = bb[oi];
        #pragma unroll
        for (int k = 0; k < HID; k++)
            acc += a[k] * wl[oi][k] + hv[k] * wr[oi][k];
        o[oi] = acc;
        ss += acc * acc;
    }
    float innorm = 1.0f / fmaxf(sqrtf(ss), 1e-12f);
    float* op = h3 + (size_t)i * NCLS;
    #pragma unroll
    for (int c = 0; c < NCLS; c++) op[c] = o[c] * innorm;
}

// ---------------------------------------------------------------------------
// K6: per-graph mean pool (batch sorted -> binary search) + softmax.
// One 64-lane wave per graph; output dtype chosen by flags[1].
__device__ __forceinline__ int lbound(const int* __restrict__ a, int n, int key, int sh) {
    int lo = 0, hi = n;
    while (lo < hi) {
        int mid = (lo + hi) >> 1;
        if (a[((size_t)mid) << sh] < key) lo = mid + 1; else hi = mid;
    }
    return lo;
}

__global__ void k_pool_softmax(const float* __restrict__ h3,
                               const int* __restrict__ batch,
                               const int* __restrict__ flags,
                               void* __restrict__ out, int n) {
    int g = blockIdx.x;
    int lane = threadIdx.x;
    int sh = flags[0];
    int lo = lbound(batch, n, g, sh);
    int hi = lbound(batch, n, g + 1, sh);
    float acc[NCLS];
    #pragma unroll
    for (int c = 0; c < NCLS; c++) acc[c] = 0.0f;
    for (int i = lo + lane; i < hi; i += 64) {
        const float* r = h3 + (size_t)i * NCLS;
        #pragma unroll
        for (int c = 0; c < NCLS; c++) acc[c] += r[c];
    }
    #pragma unroll
    for (int c = 0; c < NCLS; c++) {
        #pragma unroll
        for (int off = 1; off < 64; off <<= 1)
            acc[c] += __shfl_xor(acc[c], off);
    }
    float invc = 1.0f / fmaxf((float)(hi - lo), 1.0f);
    float m = -1e30f;
    #pragma unroll
    for (int c = 0; c < NCLS; c++) { acc[c] *= invc; m = fmaxf(m, acc[c]); }
    float s = 0.0f;
    #pragma unroll
    for (int c = 0; c < NCLS; c++) { acc[c] = expf(acc[c] - m); s += acc[c]; }
    float invs = 1.0f / s;
    if (lane < NCLS) {
        float v = acc[lane] * invs;
        size_t idx = (size_t)g * NCLS + lane;
        if (flags[1]) ((__hip_bfloat16*)out)[idx] = __float2bfloat16(v);
        else          ((float*)out)[idx] = v;
    }
}

// ---------------------------------------------------------------------------
extern "C" void kernel_launch(void* const* d_in, const int* in_sizes, int n_in,
                              void* d_out, int out_size, void* d_ws, size_t ws_size,
                              hipStream_t stream) {
    const void* x   = d_in[0];
    const int*  ei  = (const int*)d_in[1];
    const int*  bat = (const int*)d_in[2];
    const void* emb = d_in[3];
    const void* W1l = d_in[4];  const void* b1 = d_in[5];  const void* W1r = d_in[6];
    const void* W2l = d_in[7];  const void* b2 = d_in[8];  const void* W2r = d_in[9];
    const void* W3l = d_in[10]; const void* b3 = d_in[11]; const void* W3r = d_in[12];

    int n = in_sizes[0] / N_FEAT;
    int e = in_sizes[1] / 2;

    // ws layout (floats): hcur[n*16] | hnext[n*16] (reused for h3[n*10]) |
    //                     agg[n*16] | deg[n] | flags[2]
    float* hcur  = (float*)d_ws;
    float* hnext = hcur  + (size_t)n * HID;
    float* agg   = hnext + (size_t)n * HID;
    float* deg   = agg   + (size_t)n * HID;
    int*   flags = (int*)(deg + n);
    float* h3    = hnext;

    int zgrid_agg = (n * HID + 255) / 256;
    int zgrid_deg = (n + 255) / 256;
    unsigned int sgrid = (unsigned int)(((size_t)e * 16 + 255) / 256);

    // dtype probes + degrees + initial embedding
    k_detect<<<1, 64, 0, stream>>>(ei, (const unsigned int*)x, flags);
    k_zero<<<zgrid_deg, 256, 0, stream>>>(deg, n);
    k_deg<<<(e + 255) / 256, 256, 0, stream>>>(ei, flags, deg, e);
    k_argmax_embed<<<(n + 3) / 4, 256, 0, stream>>>(x, emb, flags, hcur, n);

    // layer 1
    k_zero<<<zgrid_agg, 256, 0, stream>>>(agg, n * HID);
    k_scatter<<<sgrid, 256, 0, stream>>>(ei, flags, hcur, agg, e);
    k_combine<<<(n + 255) / 256, 256, 0, stream>>>(agg, hcur, deg, W1l, b1, W1r, flags, hnext, n);

    // layer 2
    k_zero<<<zgrid_agg, 256, 0, stream>>>(agg, n * HID);
    k_scatter<<<sgrid, 256, 0, stream>>>(ei, flags, hnext, agg, e);
    k_combine<<<(n + 255) / 256, 256, 0, stream>>>(agg, hnext, deg, W2l, b2, W2r, flags, hcur, n);

    // layer 3
    k_zero<<<zgrid_agg, 256, 0, stream>>>(agg, n * HID);
    k_scatter<<<sgrid, 256, 0, stream>>>(ei, flags, hcur, agg, e);
    k_combine3<<<(n + 255) / 256, 256, 0, stream>>>(agg, hcur, deg, W3l, b3, W3r, flags, h3, n);

    // pool + softmax
    k_pool_softmax<<<NGRAPH, 64, 0, stream>>>(h3, bat, flags, d_out, n);
}